// Round 9
// baseline (1678.425 us; speedup 1.0000x reference)
//
#include <hip/hip_runtime.h>
#include <hip/hip_bf16.h>
#include <math.h>

#define NE 10
#define CAP 2048
#define MAXTILES 74

typedef __bf16 bf16x8 __attribute__((ext_vector_type(8)));
typedef __bf16 bf16x4 __attribute__((ext_vector_type(4)));
typedef float f32x4 __attribute__((ext_vector_type(4)));

#define MFMA_B16(a, b, c) __builtin_amdgcn_mfma_f32_16x16x32_bf16((a), (b), (c), 0, 0, 0)

// split fp32[8] -> hi/lo bf16x8 (v = hi + lo, |lo| ~ 2^-8 |v|)
__device__ __forceinline__ void cvt8(const float* v, bf16x8& h, bf16x8& l) {
  #pragma unroll
  for (int i = 0; i < 8; ++i) {
    __bf16 hh = (__bf16)v[i];
    h[i] = hh;
    l[i] = (__bf16)(v[i] - (float)hh);
  }
}

// ============================ zero outputs (graph-capture-safe memset) ============================
__global__ __launch_bounds__(256) void k_zero_out(float* __restrict__ p, int n4) {
  int i = blockIdx.x * 256 + threadIdx.x;
  if (i < n4) {
    float4 z = {0.f, 0.f, 0.f, 0.f};
    *(float4*)&p[(size_t)i * 4] = z;
  }
}

// ============================ patch embed ============================
__global__ __launch_bounds__(256) void k_patch_embed(const float* __restrict__ x,
    const float* __restrict__ Wp, const float* __restrict__ bp, float* __restrict__ h) {
  int t = blockIdx.x;            // 0..2047
  int b = t >> 6, p = t & 63;
  int hp = p >> 3, wp = p & 7;
  __shared__ float pv[48];
  int tid = threadIdx.x;
  if (tid < 48) {
    int c = tid >> 4, rem = tid & 15, pr = rem >> 2, pc = rem & 3;
    pv[tid] = x[((b * 3 + c) * 32 + hp * 4 + pr) * 32 + wp * 4 + pc];
  }
  __syncthreads();
  int n0 = tid * 4;
  float4 acc = *(const float4*)&bp[n0];
  #pragma unroll 8
  for (int k = 0; k < 48; ++k) {
    float s = pv[k];
    float4 w = *(const float4*)&Wp[k * 1024 + n0];
    acc.x = fmaf(s, w.x, acc.x);
    acc.y = fmaf(s, w.y, acc.y);
    acc.z = fmaf(s, w.z, acc.z);
    acc.w = fmaf(s, w.w, acc.w);
  }
  *(float4*)&h[(size_t)t * 1024 + n0] = acc;
}

// ============================ layernorm (+ optional bf16 hi/lo planes) ============================
__device__ __forceinline__ float blk_reduce(float v, float* sb) {
  #pragma unroll
  for (int o = 32; o; o >>= 1) v += __shfl_down(v, o);
  int w = threadIdx.x >> 6, lane = threadIdx.x & 63;
  if (lane == 0) sb[w] = v;
  __syncthreads();
  if (threadIdx.x == 0) sb[0] = sb[0] + sb[1] + sb[2] + sb[3];
  __syncthreads();
  v = sb[0];
  __syncthreads();
  return v;
}

__global__ __launch_bounds__(256) void k_layernorm(const float* __restrict__ in,
    const float* __restrict__ g, const float* __restrict__ b, float* __restrict__ out,
    __bf16* __restrict__ oh, __bf16* __restrict__ ol) {
  __shared__ float sb[4];
  int t = blockIdx.x, tid = threadIdx.x;
  float4 v = *(const float4*)&in[(size_t)t * 1024 + tid * 4];
  float s = blk_reduce(v.x + v.y + v.z + v.w, sb);
  float mean = s * (1.0f / 1024.0f);
  float dx = v.x - mean, dy = v.y - mean, dz = v.z - mean, dw = v.w - mean;
  float sq = blk_reduce(dx * dx + dy * dy + dz * dz + dw * dw, sb);
  float var = sq * (1.0f / 1024.0f);
  float inv = 1.0f / sqrtf(var + 1e-5f);
  float4 gg = *(const float4*)&g[tid * 4];
  float4 bb = *(const float4*)&b[tid * 4];
  float4 o;
  o.x = dx * inv * gg.x + bb.x;
  o.y = dy * inv * gg.y + bb.y;
  o.z = dz * inv * gg.z + bb.z;
  o.w = dw * inv * gg.w + bb.w;
  size_t idx = (size_t)t * 1024 + tid * 4;
  *(float4*)&out[idx] = o;
  if (oh) {   // uniform branch: MoE LNs emit pre-split bf16 planes for MFMA A-operand
    bf16x4 hv, lv;
    float ov[4] = {o.x, o.y, o.z, o.w};
    #pragma unroll
    for (int i = 0; i < 4; ++i) {
      __bf16 hh = (__bf16)ov[i];
      hv[i] = hh;
      lv[i] = (__bf16)(ov[i] - (float)hh);
    }
    *(bf16x4*)&oh[idx] = hv;
    *(bf16x4*)&ol[idx] = lv;
  }
}

// ============================ dense gemm (fp32, 128x128 tile, prefetched) ============================
// Attention-path GEMMs stay pure fp32: they feed the routers (discrete top-k).
__global__ __launch_bounds__(256) void k_gemm3(const float* __restrict__ A,
    const float* __restrict__ B0, const float* __restrict__ B1, const float* __restrict__ B2,
    float* __restrict__ C, int ldc) {
  __shared__ float As[16][132];
  __shared__ float Bs[16][132];
  int wsel = blockIdx.y >> 3;
  const float* B = (wsel == 0) ? B0 : ((wsel == 1) ? B1 : B2);
  int n0 = (blockIdx.y & 7) << 7;
  int coff = wsel << 10;
  int m0 = blockIdx.x << 7;
  int tid = threadIdx.x;
  int tr = tid >> 4, tc = tid & 15;
  int lar = tid >> 1, lak = (tid & 1) << 3;       // A: 128 rows x 8 k per thread
  int lbk = tid >> 4, lbn = (tid & 15) << 3;      // B: 16 k x 128 n
  const float* aptr = A + (size_t)(m0 + lar) * 1024 + lak;
  const float* bptr = B + (size_t)lbk * 1024 + n0 + lbn;
  float acc[8][8];
  #pragma unroll
  for (int i = 0; i < 8; ++i)
    #pragma unroll
    for (int j = 0; j < 8; ++j) acc[i][j] = 0.0f;
  float4 a0 = *(const float4*)(aptr);
  float4 a1 = *(const float4*)(aptr + 4);
  float4 b0 = *(const float4*)(bptr);
  float4 b1 = *(const float4*)(bptr + 4);
  for (int k0 = 0; k0 < 1024; k0 += 16) {
    __syncthreads();
    As[lak + 0][lar] = a0.x; As[lak + 1][lar] = a0.y;
    As[lak + 2][lar] = a0.z; As[lak + 3][lar] = a0.w;
    As[lak + 4][lar] = a1.x; As[lak + 5][lar] = a1.y;
    As[lak + 6][lar] = a1.z; As[lak + 7][lar] = a1.w;
    *(float4*)&Bs[lbk][lbn] = b0;
    *(float4*)&Bs[lbk][lbn + 4] = b1;
    __syncthreads();
    if (k0 + 16 < 1024) {          // register-prefetch next K-slice
      a0 = *(const float4*)(aptr + k0 + 16);
      a1 = *(const float4*)(aptr + k0 + 20);
      b0 = *(const float4*)(bptr + (size_t)(k0 + 16) * 1024);
      b1 = *(const float4*)(bptr + (size_t)(k0 + 16) * 1024 + 4);
    }
    #pragma unroll
    for (int kk = 0; kk < 16; ++kk) {
      float4 x0 = *(const float4*)&As[kk][tr << 3];
      float4 x1 = *(const float4*)&As[kk][(tr << 3) + 4];
      float4 y0 = *(const float4*)&Bs[kk][tc << 3];
      float4 y1 = *(const float4*)&Bs[kk][(tc << 3) + 4];
      float av[8] = {x0.x, x0.y, x0.z, x0.w, x1.x, x1.y, x1.z, x1.w};
      float bv[8] = {y0.x, y0.y, y0.z, y0.w, y1.x, y1.y, y1.z, y1.w};
      #pragma unroll
      for (int i = 0; i < 8; ++i)
        #pragma unroll
        for (int j = 0; j < 8; ++j)
          acc[i][j] = fmaf(av[i], bv[j], acc[i][j]);
    }
  }
  #pragma unroll
  for (int i = 0; i < 8; ++i) {
    float* crow = C + (size_t)(m0 + (tr << 3) + i) * ldc + coff + n0 + (tc << 3);
    float4 o0 = {acc[i][0], acc[i][1], acc[i][2], acc[i][3]};
    float4 o1 = {acc[i][4], acc[i][5], acc[i][6], acc[i][7]};
    *(float4*)&crow[0] = o0;
    *(float4*)&crow[4] = o1;
  }
}

// ============================ attention core ============================
__global__ __launch_bounds__(256) void k_attn(const float* __restrict__ qkv,
                                              float* __restrict__ attnraw) {
  int blk = blockIdx.x;
  int b = blk >> 3, hd = blk & 7;
  const float* qb = qkv + (size_t)(b * 64) * 3072 + hd * 128;
  __shared__ float ks[64][132];
  __shared__ float ps[64][65];
  int tid = threadIdx.x;
  for (int idx = tid; idx < 64 * 32; idx += 256) {
    int r = idx >> 5, c4 = (idx & 31) << 2;
    *(float4*)&ks[r][c4] = *(const float4*)&qb[(size_t)r * 3072 + 1024 + c4];
  }
  __syncthreads();
  int i = tid >> 2, jg = tid & 3;
  float accs[16];
  #pragma unroll
  for (int jj = 0; jj < 16; ++jj) accs[jj] = 0.0f;
  const float* qrow = qb + (size_t)i * 3072;
  for (int d4 = 0; d4 < 128; d4 += 4) {
    float4 q4 = *(const float4*)&qrow[d4];
    #pragma unroll
    for (int jj = 0; jj < 16; ++jj) {
      int j = jg * 16 + jj;
      float4 k4 = *(const float4*)&ks[j][d4];
      accs[jj] += q4.x * k4.x + q4.y * k4.y + q4.z * k4.z + q4.w * k4.w;
    }
  }
  const float scale = 0.08838834764831845f;  // 1/sqrt(128)
  float mx = -1e30f;
  #pragma unroll
  for (int jj = 0; jj < 16; ++jj) { accs[jj] *= scale; mx = fmaxf(mx, accs[jj]); }
  mx = fmaxf(mx, __shfl_xor(mx, 1));
  mx = fmaxf(mx, __shfl_xor(mx, 2));
  float sum = 0.0f;
  #pragma unroll
  for (int jj = 0; jj < 16; ++jj) { accs[jj] = expf(accs[jj] - mx); sum += accs[jj]; }
  sum += __shfl_xor(sum, 1);
  sum += __shfl_xor(sum, 2);
  float isum = 1.0f / sum;
  #pragma unroll
  for (int jj = 0; jj < 16; ++jj) ps[i][jg * 16 + jj] = accs[jj] * isum;
  __syncthreads();
  for (int idx = tid; idx < 64 * 32; idx += 256) {
    int r = idx >> 5, c4 = (idx & 31) << 2;
    *(float4*)&ks[r][c4] = *(const float4*)&qb[(size_t)r * 3072 + 2048 + c4];
  }
  __syncthreads();
  int io = tid >> 2, dg = tid & 3;
  float acco[32];
  #pragma unroll
  for (int d = 0; d < 32; ++d) acco[d] = 0.0f;
  for (int j = 0; j < 64; ++j) {
    float pj = ps[io][j];
    #pragma unroll
    for (int dd = 0; dd < 32; dd += 4) {
      float4 v4 = *(const float4*)&ks[j][dg * 32 + dd];
      acco[dd + 0] = fmaf(pj, v4.x, acco[dd + 0]);
      acco[dd + 1] = fmaf(pj, v4.y, acco[dd + 1]);
      acco[dd + 2] = fmaf(pj, v4.z, acco[dd + 2]);
      acco[dd + 3] = fmaf(pj, v4.w, acco[dd + 3]);
    }
  }
  float* orow = attnraw + (size_t)(b * 64 + io) * 1024 + hd * 128 + dg * 32;
  #pragma unroll
  for (int dd = 0; dd < 32; dd += 4) {
    float4 o = {acco[dd], acco[dd + 1], acco[dd + 2], acco[dd + 3]};
    *(float4*)&orow[dd] = o;
  }
}

// ============================ residual + bias + pos ============================
__global__ __launch_bounds__(256) void k_resid(float* __restrict__ h, const float* __restrict__ ao,
    const float* __restrict__ bo, const float* __restrict__ pos) {
  int t = blockIdx.x, tid = threadIdx.x;
  int d4 = tid * 4;
  float4 hv = *(float4*)&h[(size_t)t * 1024 + d4];
  float4 av = *(const float4*)&ao[(size_t)t * 1024 + d4];
  float4 bv = *(const float4*)&bo[d4];
  float4 pv = *(const float4*)&pos[(size_t)(t & 63) * 1024 + d4];
  hv.x = (hv.x + (av.x + bv.x)) + pv.x;
  hv.y = (hv.y + (av.y + bv.y)) + pv.y;
  hv.z = (hv.z + (av.z + bv.z)) + pv.z;
  hv.w = (hv.w + (av.w + bv.w)) + pv.w;
  *(float4*)&h[(size_t)t * 1024 + d4] = hv;
}

// ============================ router ============================
__global__ __launch_bounds__(64) void k_zero_cnt(int* cnt) {
  if (threadIdx.x < NE) cnt[threadIdx.x] = 0;
}

__global__ __launch_bounds__(64) void k_router(const float* __restrict__ xln,
    const float* __restrict__ rW, const float* __restrict__ rb,
    const float* __restrict__ nW, const float* __restrict__ nb,
    const float* __restrict__ noise,
    int* __restrict__ cnt, int* __restrict__ list_tok, float* __restrict__ gate_list) {
  int t = blockIdx.x, lane = threadIdx.x;
  float pl[NE], pn[NE];
  #pragma unroll
  for (int e = 0; e < NE; ++e) { pl[e] = 0.0f; pn[e] = 0.0f; }
  for (int d = lane; d < 1024; d += 64) {
    float xv = xln[(size_t)t * 1024 + d];
    #pragma unroll
    for (int e = 0; e < NE; ++e) {
      pl[e] = fmaf(xv, rW[d * NE + e], pl[e]);
      pn[e] = fmaf(xv, nW[d * NE + e], pn[e]);
    }
  }
  #pragma unroll
  for (int e = 0; e < NE; ++e) {
    #pragma unroll
    for (int o = 32; o; o >>= 1) {
      pl[e] += __shfl_down(pl[e], o);
      pn[e] += __shfl_down(pn[e], o);
    }
  }
  if (lane == 0) {
    float noisy[NE];
    #pragma unroll
    for (int e = 0; e < NE; ++e) {
      float lg = pl[e] + rb[e];
      float nl = pn[e] + nb[e];
      float sp = fmaxf(nl, 0.0f) + log1pf(expf(-fabsf(nl)));  // stable softplus
      noisy[e] = lg + noise[t * NE + e] * sp;
    }
    int i0 = 0;
    #pragma unroll
    for (int e = 1; e < NE; ++e) if (noisy[e] > noisy[i0]) i0 = e;   // top_k tie rule: lowest index
    int i1 = -1; float m1 = -1e30f;
    #pragma unroll
    for (int e = 0; e < NE; ++e) if (e != i0 && noisy[e] > m1) { m1 = noisy[e]; i1 = e; }
    float ex = expf(m1 - noisy[i0]);
    float inv = 1.0f / (1.0f + ex);
    float g0 = inv, g1 = ex * inv;
    int p0 = atomicAdd(&cnt[i0], 1);
    list_tok[i0 * CAP + p0] = t; gate_list[i0 * CAP + p0] = g0;
    int p1 = atomicAdd(&cnt[i1], 1);
    list_tok[i1 * CAP + p1] = t; gate_list[i1 * CAP + p1] = g1;
  }
}

// meta: [0..9] row offsets (prefix of cnt), [10..19] tile offsets, meta[20]=total tiles
__global__ void k_finalize(const int* __restrict__ cnt, int* __restrict__ meta) {
  if (threadIdx.x == 0 && blockIdx.x == 0) {
    int off = 0, toff = 0;
    for (int e = 0; e < NE; ++e) {
      meta[e] = off;
      meta[10 + e] = toff;
      off += cnt[e];
      toff += (cnt[e] + 63) >> 6;
    }
    meta[20] = toff;
  }
}

// XCD-aware work remap (T1): flat bid -> (tile, n0block) such that each XCD gets a
// contiguous tile-major run; the ~7 tiles sharing an (expert, n0) weight slice run
// back-to-back on the same XCD -> 512KB slice stays hot in its 4MB L2.
// Requires total % 8 == 0 (2368 and 592 both are). Pure bijection: safe if dispatch
// heuristic is wrong (perf-only).
__device__ __forceinline__ void xcd_remap(int bid, int total, int& tile, int& n0b) {
  int cpx = total >> 3;
  int w = (bid & 7) * cpx + (bid >> 3);
  tile = w % MAXTILES;
  n0b = w / MAXTILES;
}

// ============================ MoE FC1: bf16x3 MFMA grouped GEMM (gather + bias + relu) ===========
// Tile 64(M) x 128(N) x 32(K-step). 4 waves in 2x2; per-wave 32x64 = 2x4 frags of 16x16.
// A read PRE-SPLIT from xh/xl bf16 planes (split once in LN, not per n0-block).
// LDS: A[64][40] hi/lo bf16 (row-major), B stored TRANSPOSED [n:128][k:40] hi/lo so the
// B-frag (lane: col=l&15, k=(l>>4)*8+[0..7]) is a contiguous 16B read. 80B rows keep
// 16B alignment and conflict-free b128 per 8-lane group.
__global__ __launch_bounds__(256) void k_moe_fc1(
    const __bf16* __restrict__ xh, const __bf16* __restrict__ xl,
    const float* __restrict__ W1, const float* __restrict__ b1,
    const int* __restrict__ cnt, const int* __restrict__ meta,
    const int* __restrict__ list_tok,
    __bf16* __restrict__ hidh, __bf16* __restrict__ hidl) {
  int tile, n0b;
  xcd_remap(blockIdx.x + blockIdx.y * MAXTILES, MAXTILES * 32, tile, n0b);
  if (tile >= meta[20]) return;
  int e = 0;
  while (tile >= meta[11 + e]) ++e;
  int lt = tile - meta[10 + e];
  int base = meta[e] + (lt << 6);
  int mrem = cnt[e] - (lt << 6);
  if (mrem > 64) mrem = 64;
  __shared__ int rows_s[64];
  __shared__ __align__(16) unsigned short AsH[64 * 40], AsL[64 * 40];
  __shared__ __align__(16) unsigned short BsH[128 * 40], BsL[128 * 40];
  int tid = threadIdx.x;
  if (tid < 64) rows_s[tid] = (tid < mrem) ? list_tok[e * CAP + (lt << 6) + tid] : 0;
  __syncthreads();
  int n0 = n0b << 7;
  // staging roles
  int ar = tid >> 2, akq = (tid & 3) << 3;            // A: row 0..63, k-chunk {0,8,16,24}
  int bn = tid & 127, bkh = (tid >> 7) << 4;          // B: col n 0..127, k-half {0,16}
  const __bf16* ahsrc = xh + (size_t)rows_s[ar] * 1024 + akq;
  const __bf16* alsrc = xl + (size_t)rows_s[ar] * 1024 + akq;
  const float* bsrc = W1 + (size_t)e * 1024 * 4096 + n0 + bn;
  bf16x8 a_h, a_l;
  float bv[16];
  // ---- load K-step 0 ----
  a_h = *(const bf16x8*)(ahsrc);
  a_l = *(const bf16x8*)(alsrc);
  #pragma unroll
  for (int i = 0; i < 16; ++i) bv[i] = bsrc[(size_t)(bkh + i) * 4096];
  // MFMA roles
  int wid = tid >> 6, lane = tid & 63;
  int wm = (wid >> 1) << 5, wn = (wid & 1) << 6;
  int lr = lane & 15, lg = lane >> 4;
  f32x4 acc[2][4];
  #pragma unroll
  for (int mi = 0; mi < 2; ++mi)
    #pragma unroll
    for (int ni = 0; ni < 4; ++ni) acc[mi][ni] = (f32x4){0.f, 0.f, 0.f, 0.f};
  for (int s = 0; s < 32; ++s) {
    bf16x8 bh0, bl0, bh1, bl1;
    cvt8(bv, bh0, bl0);
    cvt8(bv + 8, bh1, bl1);
    __syncthreads();
    *(bf16x8*)&AsH[ar * 40 + akq] = a_h;
    *(bf16x8*)&AsL[ar * 40 + akq] = a_l;
    *(bf16x8*)&BsH[bn * 40 + bkh] = bh0;
    *(bf16x8*)&BsH[bn * 40 + bkh + 8] = bh1;
    *(bf16x8*)&BsL[bn * 40 + bkh] = bl0;
    *(bf16x8*)&BsL[bn * 40 + bkh + 8] = bl1;
    __syncthreads();
    if (s + 1 < 32) {
      int k0 = (s + 1) << 5;
      a_h = *(const bf16x8*)(ahsrc + k0);
      a_l = *(const bf16x8*)(alsrc + k0);
      #pragma unroll
      for (int i = 0; i < 16; ++i) bv[i] = bsrc[(size_t)(k0 + bkh + i) * 4096];
    }
    bf16x8 aH[2], aL[2], bH[4], bL[4];
    #pragma unroll
    for (int mi = 0; mi < 2; ++mi) {
      int off = (wm + mi * 16 + lr) * 40 + lg * 8;
      aH[mi] = *(bf16x8*)&AsH[off];
      aL[mi] = *(bf16x8*)&AsL[off];
    }
    #pragma unroll
    for (int ni = 0; ni < 4; ++ni) {
      int off = (wn + ni * 16 + lr) * 40 + lg * 8;
      bH[ni] = *(bf16x8*)&BsH[off];
      bL[ni] = *(bf16x8*)&BsL[off];
    }
    #pragma unroll
    for (int mi = 0; mi < 2; ++mi)
      #pragma unroll
      for (int ni = 0; ni < 4; ++ni) {
        acc[mi][ni] = MFMA_B16(aH[mi], bH[ni], acc[mi][ni]);
        acc[mi][ni] = MFMA_B16(aH[mi], bL[ni], acc[mi][ni]);
        acc[mi][ni] = MFMA_B16(aL[mi], bH[ni], acc[mi][ni]);
      }
  }
  // epilogue: D row = (lane>>4)*4+j, col = lane&15 (guide-verified C/D layout).
  // relu output written pre-split hi/lo (split once; FC2 reads bf16 directly).
  float bias[4];
  #pragma unroll
  for (int ni = 0; ni < 4; ++ni) bias[ni] = b1[e * 4096 + n0 + wn + ni * 16 + lr];
  #pragma unroll
  for (int mi = 0; mi < 2; ++mi)
    #pragma unroll
    for (int j = 0; j < 4; ++j) {
      int r = wm + mi * 16 + lg * 4 + j;
      if (r < mrem) {
        size_t rowoff = (size_t)(base + r) * 4096 + n0 + wn + lr;
        #pragma unroll
        for (int ni = 0; ni < 4; ++ni) {
          float v = fmaxf(acc[mi][ni][j] + bias[ni], 0.0f);
          __bf16 hh = (__bf16)v;
          hidh[rowoff + ni * 16] = hh;
          hidl[rowoff + ni * 16] = (__bf16)(v - (float)hh);
        }
      }
    }
}

// ============================ MoE FC2: bf16x3 MFMA grouped GEMM (+bias, x gate) ============
// Epilogue accumulates g*(acc+bias) straight into the (pre-zeroed) output via atomicAdd:
// each output element gets exactly 2 contributions (top-2); fp32 add of 2 terms is
// commutative (bitwise) -> deterministic. Removes ybuf (17MB ws) + the combine pass.
__global__ __launch_bounds__(256) void k_moe_fc2(
    const __bf16* __restrict__ hidh, const __bf16* __restrict__ hidl,
    const float* __restrict__ W2, const float* __restrict__ b2,
    const int* __restrict__ cnt, const int* __restrict__ meta,
    const int* __restrict__ list_tok, const float* __restrict__ gate_list,
    float* __restrict__ outp) {
  int tile, n0b;
  xcd_remap(blockIdx.x + blockIdx.y * MAXTILES, MAXTILES * 8, tile, n0b);
  if (tile >= meta[20]) return;
  int e = 0;
  while (tile >= meta[11 + e]) ++e;
  int lt = tile - meta[10 + e];
  int base = meta[e] + (lt << 6);
  int mrem = cnt[e] - (lt << 6);
  if (mrem > 64) mrem = 64;
  __shared__ float gs[64];
  __shared__ int toks_s[64];
  __shared__ __align__(16) unsigned short AsH[64 * 40], AsL[64 * 40];
  __shared__ __align__(16) unsigned short BsH[128 * 40], BsL[128 * 40];
  int tid = threadIdx.x;
  if (tid < 64) {
    gs[tid] = (tid < mrem) ? gate_list[e * CAP + (lt << 6) + tid] : 0.0f;
    toks_s[tid] = (tid < mrem) ? list_tok[e * CAP + (lt << 6) + tid] : 0;
  }
  __syncthreads();
  int n0 = n0b << 7;
  int ar = tid >> 2, akq = (tid & 3) << 3;
  int bn = tid & 127, bkh = (tid >> 7) << 4;
  // pad rows (beyond mrem, last tile of last expert) read 0xAA poison: finite tiny bf16, masked on write
  const __bf16* ahsrc = hidh + (size_t)(base + ar) * 4096 + akq;
  const __bf16* alsrc = hidl + (size_t)(base + ar) * 4096 + akq;
  const float* bsrc = W2 + (size_t)e * 4096 * 1024 + n0 + bn;
  bf16x8 a_h, a_l;
  float bv[16];
  a_h = *(const bf16x8*)(ahsrc);
  a_l = *(const bf16x8*)(alsrc);
  #pragma unroll
  for (int i = 0; i < 16; ++i) bv[i] = bsrc[(size_t)(bkh + i) * 1024];
  int wid = tid >> 6, lane = tid & 63;
  int wm = (wid >> 1) << 5, wn = (wid & 1) << 6;
  int lr = lane & 15, lg = lane >> 4;
  f32x4 acc[2][4];
  #pragma unroll
  for (int mi = 0; mi < 2; ++mi)
    #pragma unroll
    for (int ni = 0; ni < 4; ++ni) acc[mi][ni] = (f32x4){0.f, 0.f, 0.f, 0.f};
  for (int s = 0; s < 128; ++s) {
    bf16x8 bh0, bl0, bh1, bl1;
    cvt8(bv, bh0, bl0);
    cvt8(bv + 8, bh1, bl1);
    __syncthreads();
    *(bf16x8*)&AsH[ar * 40 + akq] = a_h;
    *(bf16x8*)&AsL[ar * 40 + akq] = a_l;
    *(bf16x8*)&BsH[bn * 40 + bkh] = bh0;
    *(bf16x8*)&BsH[bn * 40 + bkh + 8] = bh1;
    *(bf16x8*)&BsL[bn * 40 + bkh] = bl0;
    *(bf16x8*)&BsL[bn * 40 + bkh + 8] = bl1;
    __syncthreads();
    if (s + 1 < 128) {
      int k0 = (s + 1) << 5;
      a_h = *(const bf16x8*)(ahsrc + k0);
      a_l = *(const bf16x8*)(alsrc + k0);
      #pragma unroll
      for (int i = 0; i < 16; ++i) bv[i] = bsrc[(size_t)(k0 + bkh + i) * 1024];
    }
    bf16x8 aH[2], aL[2], bH[4], bL[4];
    #pragma unroll
    for (int mi = 0; mi < 2; ++mi) {
      int off = (wm + mi * 16 + lr) * 40 + lg * 8;
      aH[mi] = *(bf16x8*)&AsH[off];
      aL[mi] = *(bf16x8*)&AsL[off];
    }
    #pragma unroll
    for (int ni = 0; ni < 4; ++ni) {
      int off = (wn + ni * 16 + lr) * 40 + lg * 8;
      bH[ni] = *(bf16x8*)&BsH[off];
      bL[ni] = *(bf16x8*)&BsL[off];
    }
    #pragma unroll
    for (int mi = 0; mi < 2; ++mi)
      #pragma unroll
      for (int ni = 0; ni < 4; ++ni) {
        acc[mi][ni] = MFMA_B16(aH[mi], bH[ni], acc[mi][ni]);
        acc[mi][ni] = MFMA_B16(aH[mi], bL[ni], acc[mi][ni]);
        acc[mi][ni] = MFMA_B16(aL[mi], bH[ni], acc[mi][ni]);
      }
  }
  float bias[4];
  #pragma unroll
  for (int ni = 0; ni < 4; ++ni) bias[ni] = b2[e * 1024 + n0 + wn + ni * 16 + lr];
  #pragma unroll
  for (int mi = 0; mi < 2; ++mi)
    #pragma unroll
    for (int j = 0; j < 4; ++j) {
      int r = wm + mi * 16 + lg * 4 + j;
      if (r < mrem) {
        float g = gs[r];
        float* drow = outp + (size_t)toks_s[r] * 1024 + n0 + wn + lr;
        #pragma unroll
        for (int ni = 0; ni < 4; ++ni)
          atomicAdd(&drow[ni * 16], g * (acc[mi][ni][j] + bias[ni]));
      }
    }
}

// ============================ feat mean + classifier ============================
__global__ __launch_bounds__(256) void k_feat(const float* __restrict__ second,
                                              float* __restrict__ feat) {
  int b = blockIdx.x, tid = threadIdx.x;
  int d4 = tid * 4;
  float4 acc = {0, 0, 0, 0};
  for (int n = 0; n < 64; ++n) {
    float4 v = *(const float4*)&second[(size_t)(b * 64 + n) * 1024 + d4];
    acc.x += v.x; acc.y += v.y; acc.z += v.z; acc.w += v.w;
  }
  acc.x *= (1.0f / 64.0f); acc.y *= (1.0f / 64.0f);
  acc.z *= (1.0f / 64.0f); acc.w *= (1.0f / 64.0f);
  *(float4*)&feat[(size_t)b * 1024 + d4] = acc;
}

__global__ __launch_bounds__(64) void k_cls(const float* __restrict__ feat,
    const float* __restrict__ Wc, const float* __restrict__ bc, float* __restrict__ cls) {
  int b = blockIdx.x, lane = threadIdx.x;
  float acc[10];
  #pragma unroll
  for (int j = 0; j < 10; ++j) acc[j] = 0.0f;
  for (int d = lane; d < 1024; d += 64) {
    float f = feat[(size_t)b * 1024 + d];
    #pragma unroll
    for (int j = 0; j < 10; ++j) acc[j] = fmaf(f, Wc[d * 10 + j], acc[j]);
  }
  #pragma unroll
  for (int j = 0; j < 10; ++j) {
    #pragma unroll
    for (int o = 32; o; o >>= 1) acc[j] += __shfl_down(acc[j], o);
  }
  if (lane == 0) {
    #pragma unroll
    for (int j = 0; j < 10; ++j) cls[b * 10 + j] = acc[j] + bc[j];
  }
}

// ============================ host launch ============================
extern "C" void kernel_launch(void* const* d_in, const int* in_sizes, int n_in,
                              void* d_out, int out_size, void* d_ws, size_t ws_size,
                              hipStream_t stream) {
  const float* x        = (const float*)d_in[0];
  const float* W_patch  = (const float*)d_in[1];
  const float* b_patch  = (const float*)d_in[2];
  const float* ln1_g    = (const float*)d_in[3];
  const float* ln1_b    = (const float*)d_in[4];
  const float* ln2_g    = (const float*)d_in[5];
  const float* ln2_b    = (const float*)d_in[6];
  const float* ln3_g    = (const float*)d_in[7];
  const float* ln3_b    = (const float*)d_in[8];
  const float* Wq       = (const float*)d_in[9];
  const float* Wk       = (const float*)d_in[10];
  const float* Wv       = (const float*)d_in[11];
  const float* Wo       = (const float*)d_in[12];
  const float* bo       = (const float*)d_in[13];
  const float* pos_emb  = (const float*)d_in[14];
  const float* route_W1 = (const float*)d_in[15];
  const float* route_b1 = (const float*)d_in[16];
  const float* noise_W1 = (const float*)d_in[17];
  const float* noise_b1 = (const float*)d_in[18];
  const float* e1_W1    = (const float*)d_in[19];
  const float* e1_b1    = (const float*)d_in[20];
  const float* e1_W2    = (const float*)d_in[21];
  const float* e1_b2    = (const float*)d_in[22];
  const float* noise1   = (const float*)d_in[23];
  const float* route_W2 = (const float*)d_in[24];
  const float* route_b2 = (const float*)d_in[25];
  const float* noise_W2 = (const float*)d_in[26];
  const float* noise_b2 = (const float*)d_in[27];
  const float* e2_W1    = (const float*)d_in[28];
  const float* e2_b1    = (const float*)d_in[29];
  const float* e2_W2    = (const float*)d_in[30];
  const float* e2_b2    = (const float*)d_in[31];
  const float* noise2   = (const float*)d_in[32];
  const float* Wc       = (const float*)d_in[33];
  const float* bc       = (const float*)d_in[34];

  // ---- workspace layout (~92MB); attention-phase and MoE-phase buffers alias ----
  float* ws = (float*)d_ws;
  float* h        = ws;                         // 2048*1024 f32
  float* xln      = h + 2097152;                // 2048*1024 f32
  __bf16* xh      = (__bf16*)(xln + 2097152);   // 2048*1024 bf16 (hi plane)
  __bf16* xl      = xh + 2097152;               // 2048*1024 bf16 (lo plane)
  float* big      = (float*)(xl + 2097152);     // max(attn phase 40MB, MoE phase 68MB)
  // attention phase:
  float* qkv      = big;                        // 2048*3072
  float* attnraw  = qkv + 6291456;              // 2048*1024
  float* attnout  = attnraw + 2097152;          // 2048*1024
  // MoE phase (reuses 'big'):
  __bf16* hidh    = (__bf16*)big;                    // 4160*4096 bf16 (hi)
  __bf16* hidl    = hidh + (size_t)4160 * 4096;      // 4160*4096 bf16 (lo)
  float* gate_list = (float*)(hidl + (size_t)4160 * 4096);  // 10*2048
  int* ip        = (int*)(gate_list + NE * CAP);
  int* cnt       = ip;                 // 10
  int* meta      = cnt + 10;           // 21
  int* list_tok  = meta + 21;          // 10*2048

  float* outFirst  = (float*)d_out;
  float* outSecond = outFirst + 2097152;
  float* outFeat   = outSecond + 2097152;
  float* outCls    = outFeat + 32768;

  // zero first|second (4M floats): FC2 accumulates into them atomically.
  // (kernel, not hipMemsetAsync: categorically graph-capture-safe)
  k_zero_out<<<4096, 256, 0, stream>>>(outFirst, 1048576);

  // ---- stage 1: patch embed + attention block (pure fp32: feeds discrete router) ----
  k_patch_embed<<<2048, 256, 0, stream>>>(x, W_patch, b_patch, h);
  k_layernorm<<<2048, 256, 0, stream>>>(h, ln1_g, ln1_b, xln, nullptr, nullptr);
  k_gemm3<<<dim3(16, 24), 256, 0, stream>>>(xln, Wq, Wk, Wv, qkv, 3072);
  k_attn<<<256, 256, 0, stream>>>(qkv, attnraw);
  k_gemm3<<<dim3(16, 8), 256, 0, stream>>>(attnraw, Wo, Wo, Wo, attnout, 1024);
  k_resid<<<2048, 256, 0, stream>>>(h, attnout, bo, pos_emb);

  // ---- MoE layers (expert FFNs in bf16x3 MFMA, ~1e-5 rel err; A pre-split once) ----
  struct MoEArgs {
    const float *lng, *lnb, *rW, *rb, *nW, *nb, *noise, *W1, *b1, *W2, *b2;
    float* outp;
  };
  MoEArgs layers[2] = {
    {ln2_g, ln2_b, route_W1, route_b1, noise_W1, noise_b1, noise1,
     e1_W1, e1_b1, e1_W2, e1_b2, outFirst},
    {ln3_g, ln3_b, route_W2, route_b2, noise_W2, noise_b2, noise2,
     e2_W1, e2_b1, e2_W2, e2_b2, outSecond},
  };
  for (int l = 0; l < 2; ++l) {
    MoEArgs& A = layers[l];
    k_layernorm<<<2048, 256, 0, stream>>>(h, A.lng, A.lnb, xln, xh, xl);
    k_zero_cnt<<<1, 64, 0, stream>>>(cnt);
    k_router<<<2048, 64, 0, stream>>>(xln, A.rW, A.rb, A.nW, A.nb, A.noise,
                                      cnt, list_tok, gate_list);
    k_finalize<<<1, 1, 0, stream>>>(cnt, meta);
    k_moe_fc1<<<dim3(MAXTILES, 32), 256, 0, stream>>>(xh, xl, A.W1, A.b1, cnt, meta,
                                                      list_tok, hidh, hidl);
    k_moe_fc2<<<dim3(MAXTILES, 8), 256, 0, stream>>>(hidh, hidl, A.W2, A.b2, cnt, meta,
                                                     list_tok, gate_list, A.outp);
  }

  // ---- head ----
  k_feat<<<32, 256, 0, stream>>>(outSecond, outFeat);
  k_cls<<<32, 64, 0, stream>>>(outFeat, Wc, bc, outCls);
}